// Round 9
// baseline (289.550 us; speedup 1.0000x reference)
//
#include <hip/hip_runtime.h>
#include <hip/hip_cooperative_groups.h>

namespace cg = cooperative_groups;

// N=65536 nodes, D=64 feat, K=32 topk, E=N*16 edges (sorted edge_dst).
// Round-9 (post-mortem R8: agg pinned by gather latency; ~22us of dispatch
// gaps is the biggest controllable item; harness ws-poison fill ~43us fixed):
//  ONE cooperative kernel, grid-wide sync between phases:
//   phase 1: CSR indptr boundary-detect + bf16 dense build (wave-private LDS
//            rows, ds_add scatter, no block barriers).
//   grid.sync()  — replaces a full dispatch boundary.
//   phase 2: agg, lane = slot(0..7)*8 + feat_octet(0..7), one node per slot
//            (8192 waves x 8 = 65536, single pass), uint4 row gathers,
//            in-register completion, no shfl, direct 2x float4 store.
//  2048 blocks x 256 = 8 blocks/CU resident; launch_bounds(256,8) caps VGPR
//  at 64 (both phases were <=24 VGPR standalone) for cooperative residency.

#define DFEAT 64
#define KTOP  32

__device__ __forceinline__ unsigned short f2bf(float x) {
    unsigned u = __float_as_uint(x);
    u += 0x7fffu + ((u >> 16) & 1u);               // round-to-nearest-even
    return (unsigned short)(u >> 16);
}
__device__ __forceinline__ float bfu(unsigned int u16) {
    return __uint_as_float(u16 << 16);
}

__global__ __launch_bounds__(256, 8) void fused_kernel(
    const float*  __restrict__ topk_v,
    const int*    __restrict__ topk_i,
    const int*    __restrict__ edge_dst,
    const int*    __restrict__ edge_src,
    const float4* __restrict__ feat4,
    const float*  __restrict__ eps,
    unsigned int* __restrict__ dense16,   // 32 words (64 bf16) per node
    int*          __restrict__ indptr,
    float4*       __restrict__ out4,
    int n_nodes, int n_edges)
{
    __shared__ float rows[4][2 * DFEAT];  // wave-private 2-node rows
    int tid    = blockIdx.x * blockDim.x + threadIdx.x;
    int stride = gridDim.x * blockDim.x;
    int lane   = threadIdx.x & 63;
    int wid    = threadIdx.x >> 6;
    int wave   = tid >> 6;
    int nwaves = stride >> 6;

    // ---- Phase 1a: indptr[node] = first edge with dst >= node; indptr[n]=E.
    for (int e = tid; e < n_edges; e += stride) {
        int cur  = edge_dst[e];
        int prev = (e == 0) ? -1 : edge_dst[e - 1];
        for (int node = prev + 1; node <= cur; ++node) indptr[node] = e;
        if (e == n_edges - 1) {
            for (int node = cur + 1; node <= n_nodes; ++node) indptr[node] = n_edges;
        }
    }

    // ---- Phase 1b: bf16 dense rows, 2 nodes per wave trip, no block
    // barriers (rows are wave-private; wave DS ops are program-ordered).
    {
        int half = lane >> 5;
        int total_pairs = n_nodes >> 1;
        for (int pair = wave; pair < total_pairs; pair += nwaves) {
            int nodeA = pair * 2;

            rows[wid][lane]      = 0.0f;
            rows[wid][lane + 64] = 0.0f;

            size_t base = (size_t)nodeA * KTOP;   // A's 32 pairs then B's 32
            int   idx = topk_i[base + lane];
            float val = topk_v[base + lane];
            atomicAdd(&rows[wid][half * DFEAT + idx], val);  // ds_add, dup-safe

            float a = rows[wid][2 * lane];
            float b = rows[wid][2 * lane + 1];
            dense16[nodeA * 32 + lane] =
                (unsigned int)f2bf(a) | ((unsigned int)f2bf(b) << 16);
        }
    }

    // ---- Grid-wide barrier: dense16/indptr globally visible before gather.
    cg::this_grid().sync();

    // ---- Phase 2: aggregate. slot s of wave w owns node w*8+s; the slot's
    // 8 lanes hold the node's full 64-feature row (uint4 = 8 bf16 / lane).
    const uint4* d16q = (const uint4*)dense16;
    int f    = lane & 7;
    int slot = lane >> 3;
    float sc = 1.0f + eps[0];

    for (int g = wave; g * 8 < n_nodes; g += nwaves) {
        int node = g * 8 + slot;
        if (node < n_nodes) {
            int s = indptr[node];
            int e = indptr[node + 1];

            float acc[8] = {0, 0, 0, 0, 0, 0, 0, 0};
            for (int base = s; base < e; base += 4) {
#pragma unroll
                for (int u = 0; u < 4; ++u) {   // 4 independent gather chains
                    int ee = base + u;
                    if (ee < e) {
                        int src = edge_src[ee];               // 8-lane broadcast
                        uint4 r = d16q[(size_t)src * 8 + f];  // 8 rows per instr
                        acc[0] += bfu(r.x & 0xffffu); acc[1] += bfu(r.x >> 16);
                        acc[2] += bfu(r.y & 0xffffu); acc[3] += bfu(r.y >> 16);
                        acc[4] += bfu(r.z & 0xffffu); acc[5] += bfu(r.z >> 16);
                        acc[6] += bfu(r.w & 0xffffu); acc[7] += bfu(r.w >> 16);
                    }
                }
            }

            float4 ft0 = feat4[(size_t)node * 16 + 2 * f];
            float4 ft1 = feat4[(size_t)node * 16 + 2 * f + 1];
            float4 o0, o1;
            o0.x = sc * ft0.x + acc[0];
            o0.y = sc * ft0.y + acc[1];
            o0.z = sc * ft0.z + acc[2];
            o0.w = sc * ft0.w + acc[3];
            o1.x = sc * ft1.x + acc[4];
            o1.y = sc * ft1.y + acc[5];
            o1.z = sc * ft1.z + acc[6];
            o1.w = sc * ft1.w + acc[7];
            out4[(size_t)node * 16 + 2 * f]     = o0;
            out4[(size_t)node * 16 + 2 * f + 1] = o1;
        }
    }
}

extern "C" void kernel_launch(void* const* d_in, const int* in_sizes, int n_in,
                              void* d_out, int out_size, void* d_ws, size_t ws_size,
                              hipStream_t stream)
{
    const float*  feat     = (const float*)d_in[0];
    const float*  topk_v   = (const float*)d_in[1];
    const float*  eps      = (const float*)d_in[2];
    const int*    topk_i   = (const int*)d_in[3];
    const int*    edge_src = (const int*)d_in[4];
    const int*    edge_dst = (const int*)d_in[5];
    float4*       out      = (float4*)d_out;

    int n_nodes = in_sizes[0] / DFEAT;
    int n_edges = in_sizes[4];

    // ws layout: [dense16: n*64*2 B] [indptr: (n+1)*4 B]
    unsigned int* dense16 = (unsigned int*)d_ws;
    size_t d16_bytes = (size_t)n_nodes * DFEAT * sizeof(unsigned short);
    size_t d16_pad   = (d16_bytes + 255) & ~(size_t)255;
    int*   indptr    = (int*)((char*)d_ws + d16_pad);

    const float4* feat4 = (const float4*)feat;
    void* args[] = {
        (void*)&topk_v, (void*)&topk_i, (void*)&edge_dst, (void*)&edge_src,
        (void*)&feat4, (void*)&eps, (void*)&dense16, (void*)&indptr,
        (void*)&out, (void*)&n_nodes, (void*)&n_edges,
    };
    hipLaunchCooperativeKernel((const void*)fused_kernel, dim3(2048), dim3(256),
                               args, 0, stream);
}

// Round 10
// 131.009 us; speedup vs baseline: 2.2101x; 2.2101x over previous
//
#include <hip/hip_runtime.h>

// N=65536 nodes, D=64 feat, K=32 topk, E=N*16 edges (sorted edge_dst).
// Round-10 (post-mortem R9: cooperative grid.sync = ~150us on MI355X —
// cross-XCD spin + coherence fence; REVERTED to R8 two-kernel structure).
// New in R10: non-temporal (evict-first) hints on all STREAMING traffic
// (feat reads, out stores, edge_src, topk_v/topk_i) so the 4MB/XCD L2 is
// reserved for the random 128B dense16 row gathers (8MB working set).
//  1. prep (2048 WGs): indptr boundary-detect + bf16 dense build,
//     wave-private LDS rows, ds_add scatter, no block barriers.
//  2. agg: lane = slot(0..7)*8 + feat_octet(0..7), one node per slot
//     (8192 waves x 8 = 65536, single pass), uint4 row gathers, in-register
//     completion (no shfl), nt feat/out streaming.

#define DFEAT 64
#define KTOP  32

__device__ __forceinline__ unsigned short f2bf(float x) {
    unsigned u = __float_as_uint(x);
    u += 0x7fffu + ((u >> 16) & 1u);               // round-to-nearest-even
    return (unsigned short)(u >> 16);
}
__device__ __forceinline__ float bfu(unsigned int u16) {
    return __uint_as_float(u16 << 16);
}

typedef float  __attribute__((ext_vector_type(4))) fvec4;

__device__ __forceinline__ float4 ntload4(const float4* p) {
    fvec4 v = __builtin_nontemporal_load((const fvec4*)p);
    return make_float4(v.x, v.y, v.z, v.w);
}
__device__ __forceinline__ void ntstore4(float4* p, float4 v) {
    fvec4 t = {v.x, v.y, v.z, v.w};
    __builtin_nontemporal_store(t, (fvec4*)p);
}

__global__ __launch_bounds__(256) void prep_kernel(
    const float* __restrict__ topk_v,
    const int*   __restrict__ topk_i,
    const int*   __restrict__ edge_dst,
    unsigned int* __restrict__ dense16,   // 32 words (64 bf16) per node
    int*          __restrict__ indptr,
    int n_nodes, int n_edges)
{
    __shared__ float rows[4][2 * DFEAT];  // wave-private 2-node rows
    int tid    = blockIdx.x * blockDim.x + threadIdx.x;
    int stride = gridDim.x * blockDim.x;
    int lane   = threadIdx.x & 63;
    int wid    = threadIdx.x >> 6;
    int wave   = tid >> 6;
    int nwaves = stride >> 6;
    int half   = lane >> 5;

    // Part A: indptr[node] = first edge with dst >= node; indptr[n]=E.
    // edge_dst is read twice per element (cur + prev) -> keep cached.
    for (int e = tid; e < n_edges; e += stride) {
        int cur  = edge_dst[e];
        int prev = (e == 0) ? -1 : edge_dst[e - 1];
        for (int node = prev + 1; node <= cur; ++node) indptr[node] = e;
        if (e == n_edges - 1) {
            for (int node = cur + 1; node <= n_nodes; ++node) indptr[node] = n_edges;
        }
    }

    // Part B: bf16 dense rows, 2 nodes per wave trip, no block barriers
    // (rows are wave-private; wave DS ops are program-ordered).
    int total_pairs = n_nodes >> 1;
    for (int pair = wave; pair < total_pairs; pair += nwaves) {
        int nodeA = pair * 2;

        rows[wid][lane]      = 0.0f;
        rows[wid][lane + 64] = 0.0f;

        size_t base = (size_t)nodeA * KTOP;       // A's 32 pairs then B's 32
        int   idx = __builtin_nontemporal_load(&topk_i[base + lane]);
        float val = __builtin_nontemporal_load(&topk_v[base + lane]);
        atomicAdd(&rows[wid][half * DFEAT + idx], val);   // ds_add, dup-safe

        float a = rows[wid][2 * lane];
        float b = rows[wid][2 * lane + 1];
        dense16[nodeA * 32 + lane] =
            (unsigned int)f2bf(a) | ((unsigned int)f2bf(b) << 16);
    }
}

// Aggregate: lane = slot(0..7)*8 + f(0..7); slot s of wave w owns node
// w*8+s. Lane holds bf16 features [8f, 8f+8) of its node's row.
__global__ __launch_bounds__(256) void aggregate_bf16_kernel(
    const uint4*  __restrict__ d16q,    // row = 8 x uint4 (64 bf16, 128B)
    const float4* __restrict__ feat4,
    const float*  __restrict__ eps,
    const int*    __restrict__ edge_src,
    const int*    __restrict__ indptr,
    float4*       __restrict__ out4,
    int n_nodes)
{
    int lane = threadIdx.x & 63;
    int f    = lane & 7;     // feature octet
    int slot = lane >> 3;    // node slot within wave
    int wave = (blockIdx.x * blockDim.x + threadIdx.x) >> 6;
    int node = wave * 8 + slot;
    if (node >= n_nodes) return;          // safe: no shfl/barriers below

    float sc = 1.0f + eps[0];
    int s = indptr[node];
    int e = indptr[node + 1];

    float acc[8] = {0, 0, 0, 0, 0, 0, 0, 0};
    for (int base = s; base < e; base += 4) {
#pragma unroll
        for (int u = 0; u < 4; ++u) {     // 4 independent gather chains
            int ee = base + u;
            if (ee < e) {
                int src = __builtin_nontemporal_load(&edge_src[ee]);
                uint4 r = d16q[(size_t)src * 8 + f];  // gather: keep cached
                acc[0] += bfu(r.x & 0xffffu); acc[1] += bfu(r.x >> 16);
                acc[2] += bfu(r.y & 0xffffu); acc[3] += bfu(r.y >> 16);
                acc[4] += bfu(r.z & 0xffffu); acc[5] += bfu(r.z >> 16);
                acc[6] += bfu(r.w & 0xffffu); acc[7] += bfu(r.w >> 16);
            }
        }
    }

    float4 ft0 = ntload4(&feat4[(size_t)node * 16 + 2 * f]);
    float4 ft1 = ntload4(&feat4[(size_t)node * 16 + 2 * f + 1]);
    float4 o0, o1;
    o0.x = sc * ft0.x + acc[0];
    o0.y = sc * ft0.y + acc[1];
    o0.z = sc * ft0.z + acc[2];
    o0.w = sc * ft0.w + acc[3];
    o1.x = sc * ft1.x + acc[4];
    o1.y = sc * ft1.y + acc[5];
    o1.z = sc * ft1.z + acc[6];
    o1.w = sc * ft1.w + acc[7];
    ntstore4(&out4[(size_t)node * 16 + 2 * f],     o0);
    ntstore4(&out4[(size_t)node * 16 + 2 * f + 1], o1);
}

extern "C" void kernel_launch(void* const* d_in, const int* in_sizes, int n_in,
                              void* d_out, int out_size, void* d_ws, size_t ws_size,
                              hipStream_t stream)
{
    const float* feat     = (const float*)d_in[0];
    const float* topk_v   = (const float*)d_in[1];
    const float* eps      = (const float*)d_in[2];
    const int*   topk_i   = (const int*)d_in[3];
    const int*   edge_src = (const int*)d_in[4];
    const int*   edge_dst = (const int*)d_in[5];
    float*       out      = (float*)d_out;

    int n_nodes = in_sizes[0] / DFEAT;
    int n_edges = in_sizes[4];

    // ws layout: [dense16: n*64*2 B] [indptr: (n+1)*4 B]
    unsigned int* dense16 = (unsigned int*)d_ws;
    size_t d16_bytes = (size_t)n_nodes * DFEAT * sizeof(unsigned short);
    size_t d16_pad   = (d16_bytes + 255) & ~(size_t)255;
    int*   indptr    = (int*)((char*)d_ws + d16_pad);

    prep_kernel<<<2048, 256, 0, stream>>>(topk_v, topk_i, edge_dst,
                                          dense16, indptr, n_nodes, n_edges);

    int agg_waves  = (n_nodes + 7) / 8;              // one 8-node wave each
    int agg_blocks = (agg_waves * 64 + 255) / 256;   // 4 waves per block
    aggregate_bf16_kernel<<<agg_blocks, 256, 0, stream>>>(
        (const uint4*)dense16, (const float4*)feat, eps, edge_src,
        indptr, (float4*)out, n_nodes);
}

// Round 11
// 116.679 us; speedup vs baseline: 2.4816x; 1.1228x over previous
//
#include <hip/hip_runtime.h>

// N=65536 nodes, D=64 feat, K=32 topk, E=N*16 edges (sorted edge_dst).
// Round-11 (post-mortem R10: nt hints regressed — reverted. R9: grid.sync
// ~150us — never again. R8 = 124.5us baseline):
//  agg change: break the src->row dependent chain. Per 16-edge chunk:
//   phase A: each of the slot's 8 lanes loads 2 src indices (coalesced —
//            the wave's 8 slots cover ~128 contiguous CSR edges);
//   phase B: distribute via __shfl within the 8-lane group -> issue 16
//            INDEPENDENT 128B row gathers (no dependent address chain).
//  prep unchanged from R8 (barrier-free wave-private LDS build).

#define DFEAT 64
#define KTOP  32

__device__ __forceinline__ unsigned short f2bf(float x) {
    unsigned u = __float_as_uint(x);
    u += 0x7fffu + ((u >> 16) & 1u);               // round-to-nearest-even
    return (unsigned short)(u >> 16);
}
__device__ __forceinline__ float bfu(unsigned int u16) {
    return __uint_as_float(u16 << 16);
}

__global__ __launch_bounds__(256) void prep_kernel(
    const float* __restrict__ topk_v,
    const int*   __restrict__ topk_i,
    const int*   __restrict__ edge_dst,
    unsigned int* __restrict__ dense16,   // 32 words (64 bf16) per node
    int*          __restrict__ indptr,
    int n_nodes, int n_edges)
{
    __shared__ float rows[4][2 * DFEAT];  // wave-private 2-node rows
    int tid    = blockIdx.x * blockDim.x + threadIdx.x;
    int stride = gridDim.x * blockDim.x;
    int lane   = threadIdx.x & 63;
    int wid    = threadIdx.x >> 6;
    int wave   = tid >> 6;
    int nwaves = stride >> 6;
    int half   = lane >> 5;

    // Part A: indptr[node] = first edge with dst >= node; indptr[n]=E.
    for (int e = tid; e < n_edges; e += stride) {
        int cur  = edge_dst[e];
        int prev = (e == 0) ? -1 : edge_dst[e - 1];
        for (int node = prev + 1; node <= cur; ++node) indptr[node] = e;
        if (e == n_edges - 1) {
            for (int node = cur + 1; node <= n_nodes; ++node) indptr[node] = n_edges;
        }
    }

    // Part B: bf16 dense rows, 2 nodes per wave trip, no block barriers
    // (rows are wave-private; wave DS ops are program-ordered).
    int total_pairs = n_nodes >> 1;
    for (int pair = wave; pair < total_pairs; pair += nwaves) {
        int nodeA = pair * 2;

        rows[wid][lane]      = 0.0f;
        rows[wid][lane + 64] = 0.0f;

        size_t base = (size_t)nodeA * KTOP;       // A's 32 pairs then B's 32
        int   idx = topk_i[base + lane];
        float val = topk_v[base + lane];
        atomicAdd(&rows[wid][half * DFEAT + idx], val);   // ds_add, dup-safe

        float a = rows[wid][2 * lane];
        float b = rows[wid][2 * lane + 1];
        dense16[nodeA * 32 + lane] =
            (unsigned int)f2bf(a) | ((unsigned int)f2bf(b) << 16);
    }
}

// Aggregate: lane = slot(0..7)*8 + f(0..7); slot s of wave w owns node
// w*8+s. Lane holds bf16 features [8f, 8f+8) of its node's row.
__global__ __launch_bounds__(256) void aggregate_bf16_kernel(
    const uint4*  __restrict__ d16q,    // row = 8 x uint4 (64 bf16, 128B)
    const float4* __restrict__ feat4,
    const float*  __restrict__ eps,
    const int*    __restrict__ edge_src,
    const int*    __restrict__ indptr,
    float4*       __restrict__ out4,
    int n_nodes)
{
    int lane = threadIdx.x & 63;
    int f    = lane & 7;     // feature octet / lane-in-slot
    int slot = lane >> 3;    // node slot within wave
    int wave = (blockIdx.x * blockDim.x + threadIdx.x) >> 6;
    int node = wave * 8 + slot;
    if (node >= n_nodes) return;

    float sc = 1.0f + eps[0];
    int s = indptr[node];
    int e = indptr[node + 1];

    float acc[8] = {0, 0, 0, 0, 0, 0, 0, 0};
    for (int base = s; base < e; base += 16) {
        // Phase A: coalesced src prefetch — slot's lanes grab 16 edges.
        int i0 = base + f;
        int i1 = base + 8 + f;
        int src0 = (i0 < e) ? edge_src[i0] : -1;
        int src1 = (i1 < e) ? edge_src[i1] : -1;

        // Phase B: 16 independent row gathers (shfl only distributes the
        // already-loaded index; no load-dependent address chain).
#pragma unroll
        for (int j = 0; j < 16; ++j) {
            int sj = __shfl(j < 8 ? src0 : src1, slot * 8 + (j & 7), 64);
            if (sj >= 0) {
                uint4 r = d16q[(size_t)sj * 8 + f];   // 8 rows per instr
                acc[0] += bfu(r.x & 0xffffu); acc[1] += bfu(r.x >> 16);
                acc[2] += bfu(r.y & 0xffffu); acc[3] += bfu(r.y >> 16);
                acc[4] += bfu(r.z & 0xffffu); acc[5] += bfu(r.z >> 16);
                acc[6] += bfu(r.w & 0xffffu); acc[7] += bfu(r.w >> 16);
            }
        }
    }

    float4 ft0 = feat4[(size_t)node * 16 + 2 * f];
    float4 ft1 = feat4[(size_t)node * 16 + 2 * f + 1];
    float4 o0, o1;
    o0.x = sc * ft0.x + acc[0];
    o0.y = sc * ft0.y + acc[1];
    o0.z = sc * ft0.z + acc[2];
    o0.w = sc * ft0.w + acc[3];
    o1.x = sc * ft1.x + acc[4];
    o1.y = sc * ft1.y + acc[5];
    o1.z = sc * ft1.z + acc[6];
    o1.w = sc * ft1.w + acc[7];
    out4[(size_t)node * 16 + 2 * f]     = o0;
    out4[(size_t)node * 16 + 2 * f + 1] = o1;
}

extern "C" void kernel_launch(void* const* d_in, const int* in_sizes, int n_in,
                              void* d_out, int out_size, void* d_ws, size_t ws_size,
                              hipStream_t stream)
{
    const float* feat     = (const float*)d_in[0];
    const float* topk_v   = (const float*)d_in[1];
    const float* eps      = (const float*)d_in[2];
    const int*   topk_i   = (const int*)d_in[3];
    const int*   edge_src = (const int*)d_in[4];
    const int*   edge_dst = (const int*)d_in[5];
    float*       out      = (float*)d_out;

    int n_nodes = in_sizes[0] / DFEAT;
    int n_edges = in_sizes[4];

    // ws layout: [dense16: n*64*2 B] [indptr: (n+1)*4 B]
    unsigned int* dense16 = (unsigned int*)d_ws;
    size_t d16_bytes = (size_t)n_nodes * DFEAT * sizeof(unsigned short);
    size_t d16_pad   = (d16_bytes + 255) & ~(size_t)255;
    int*   indptr    = (int*)((char*)d_ws + d16_pad);

    prep_kernel<<<2048, 256, 0, stream>>>(topk_v, topk_i, edge_dst,
                                          dense16, indptr, n_nodes, n_edges);

    int agg_waves  = (n_nodes + 7) / 8;              // one 8-node wave each
    int agg_blocks = (agg_waves * 64 + 255) / 256;   // 4 waves per block
    aggregate_bf16_kernel<<<agg_blocks, 256, 0, stream>>>(
        (const uint4*)dense16, (const float4*)feat, eps, edge_src,
        indptr, (float4*)out, n_nodes);
}